// Round 1
// baseline (95.767 us; speedup 1.0000x reference)
//
#include <hip/hip_runtime.h>

// Problem constants (B,K,S1,S2,S3) = (4,8,64,64,64)
#define SB 4
#define SK 8
#define KM1 7
#define NBK (SB * KM1)      // 28 (b,k) pairs with k < K-1
#define NVOX (64 * 64 * 64) // 262144 voxels
#define NV4 (NVOX / 4)      // 65536 float4s
#define CHUNKS 16           // blocks per (b,k) in the moments pass
#define GSTEP (2.0f / 63.0f)

// ---------------------------------------------------------------------------
// ws layout (floats):
//   [0 .. 112)    moments: per bk: {sum, mx, my, mz}
//   [128 .. 464)  coefficients: per bk: {M00..M22, d0, d1, d2} (12 floats)
// ---------------------------------------------------------------------------

__global__ void zero_ws_kernel(float* __restrict__ ws) {
    int t = threadIdx.x;
    if (t < NBK * 4) ws[t] = 0.0f;
}

// Pass 1: per-(b,k) mask sum and first moments against the analytic grid.
__global__ __launch_bounds__(256) void moments_kernel(
        const float* __restrict__ mask, float* __restrict__ mom) {
    const int bk = blockIdx.x / CHUNKS;
    const int chunk = blockIdx.x % CHUNKS;
    const int b = bk / KM1;
    const int k = bk % KM1;
    const float4* m4 = (const float4*)(mask + (size_t)(b * SK + k) * NVOX);

    float s = 0.f, mx = 0.f, my = 0.f, mz = 0.f;
    const int base = chunk * (NV4 / CHUNKS) + threadIdx.x;
#pragma unroll
    for (int it = 0; it < (NV4 / CHUNKS) / 256; ++it) {
        const int v4 = base + it * 256;
        const float4 m = m4[v4];
        const int v = v4 << 2;
        const int i = v >> 12;
        const int j = (v >> 6) & 63;
        const int l = v & 63;
        const float gx = -1.0f + i * GSTEP;
        const float gy = -1.0f + j * GSTEP;
        const float gz = -1.0f + l * GSTEP;
        const float msum = m.x + m.y + m.z + m.w;
        s  += msum;
        mx += gx * msum;
        my += gy * msum;
        mz += gz * m.x + (gz + GSTEP) * m.y + (gz + 2.f * GSTEP) * m.z
            + (gz + 3.f * GSTEP) * m.w;
    }

    // wave (64-lane) butterfly reduce
#pragma unroll
    for (int off = 32; off > 0; off >>= 1) {
        s  += __shfl_down(s,  off, 64);
        mx += __shfl_down(mx, off, 64);
        my += __shfl_down(my, off, 64);
        mz += __shfl_down(mz, off, 64);
    }
    __shared__ float red[4][4];
    const int wave = threadIdx.x >> 6;
    const int lane = threadIdx.x & 63;
    if (lane == 0) {
        red[wave][0] = s; red[wave][1] = mx; red[wave][2] = my; red[wave][3] = mz;
    }
    __syncthreads();
    if (threadIdx.x == 0) {
        float a0 = 0.f, a1 = 0.f, a2 = 0.f, a3 = 0.f;
#pragma unroll
        for (int w = 0; w < 4; ++w) {
            a0 += red[w][0]; a1 += red[w][1]; a2 += red[w][2]; a3 += red[w][3];
        }
        atomicAdd(&mom[bk * 4 + 0], a0);
        atomicAdd(&mom[bk * 4 + 1], a1);
        atomicAdd(&mom[bk * 4 + 2], a2);
        atomicAdd(&mom[bk * 4 + 3], a3);
    }
}

// Pass 2: per-(b,k) affine coefficients M = R - I, d = p - R p + t.
__global__ void coeff_kernel(const float* __restrict__ mom,
                             const float* __restrict__ trans,
                             const float* __restrict__ rot,
                             float* __restrict__ coef) {
    const int t = threadIdx.x;
    if (t >= NBK) return;
    const float s  = mom[t * 4 + 0];
    const float p0 = mom[t * 4 + 1] / s;
    const float p1 = mom[t * 4 + 2] / s;
    const float p2 = mom[t * 4 + 3] / s;
    const float* R  = rot + t * 9;
    const float* tv = trans + t * 3;
    float* c = coef + t * 12;
    c[0] = R[0] - 1.0f; c[1] = R[1];        c[2] = R[2];
    c[3] = R[3];        c[4] = R[4] - 1.0f; c[5] = R[5];
    c[6] = R[6];        c[7] = R[7];        c[8] = R[8] - 1.0f;
    c[9]  = p0 - (R[0] * p0 + R[1] * p1 + R[2] * p2) + tv[0];
    c[10] = p1 - (R[3] * p0 + R[4] * p1 + R[5] * p2) + tv[1];
    c[11] = p2 - (R[6] * p0 + R[7] * p1 + R[8] * p2) + tv[2];
}

// Pass 3: out[b,c,v] = sum_k mask[b,k,v] * (M_k g_v + d_k)_c
__global__ __launch_bounds__(256) void output_kernel(
        const float* __restrict__ mask, const float* __restrict__ coef,
        float* __restrict__ out) {
    const int b = blockIdx.y;
    __shared__ float cf[KM1 * 12];
    if (threadIdx.x < KM1 * 12) cf[threadIdx.x] = coef[b * KM1 * 12 + threadIdx.x];
    __syncthreads();

    const int v4 = blockIdx.x * 256 + threadIdx.x;
    const int v = v4 << 2;
    const int i = v >> 12;
    const int j = (v >> 6) & 63;
    const int l = v & 63;
    const float gx = -1.0f + i * GSTEP;
    const float gy = -1.0f + j * GSTEP;
    const float gz0 = -1.0f + l * GSTEP;
    const float gz1 = gz0 + GSTEP, gz2 = gz0 + 2.f * GSTEP, gz3 = gz0 + 3.f * GSTEP;

    float4 o0 = {0, 0, 0, 0}, o1 = {0, 0, 0, 0}, o2 = {0, 0, 0, 0};
    const float4* m4 = (const float4*)mask + (size_t)b * SK * NV4 + v4;
#pragma unroll
    for (int k = 0; k < KM1; ++k) {
        const float4 m = m4[k * NV4];
        const float* c = cf + k * 12;
        const float tx = c[0] * gx + c[1] * gy + c[9];
        const float ty = c[3] * gx + c[4] * gy + c[10];
        const float tz = c[6] * gx + c[7] * gy + c[11];
        o0.x += m.x * fmaf(c[2], gz0, tx);
        o0.y += m.y * fmaf(c[2], gz1, tx);
        o0.z += m.z * fmaf(c[2], gz2, tx);
        o0.w += m.w * fmaf(c[2], gz3, tx);
        o1.x += m.x * fmaf(c[5], gz0, ty);
        o1.y += m.y * fmaf(c[5], gz1, ty);
        o1.z += m.z * fmaf(c[5], gz2, ty);
        o1.w += m.w * fmaf(c[5], gz3, ty);
        o2.x += m.x * fmaf(c[8], gz0, tz);
        o2.y += m.y * fmaf(c[8], gz1, tz);
        o2.z += m.z * fmaf(c[8], gz2, tz);
        o2.w += m.w * fmaf(c[8], gz3, tz);
    }
    float4* out4 = (float4*)out;
    out4[((size_t)b * 3 + 0) * NV4 + v4] = o0;
    out4[((size_t)b * 3 + 1) * NV4 + v4] = o1;
    out4[((size_t)b * 3 + 2) * NV4 + v4] = o2;
}

extern "C" void kernel_launch(void* const* d_in, const int* in_sizes, int n_in,
                              void* d_out, int out_size, void* d_ws, size_t ws_size,
                              hipStream_t stream) {
    const float* mask  = (const float*)d_in[0]; // (4,8,64,64,64)
    const float* trans = (const float*)d_in[1]; // (4,7,3)
    const float* rot   = (const float*)d_in[2]; // (4,7,3,3)
    // d_in[3] (grids) unused: coordinates computed analytically.
    float* out = (float*)d_out;                 // (4,3,64,64,64)
    float* mom  = (float*)d_ws;                 // 112 floats
    float* coef = (float*)d_ws + 128;           // 336 floats

    zero_ws_kernel<<<1, 128, 0, stream>>>(mom);
    moments_kernel<<<NBK * CHUNKS, 256, 0, stream>>>(mask, mom);
    coeff_kernel<<<1, 32, 0, stream>>>(mom, trans, rot, coef);
    output_kernel<<<dim3(NV4 / 256, SB), 256, 0, stream>>>(mask, coef, out);
}